// Round 7
// baseline (543.156 us; speedup 1.0000x reference)
//
#include <hip/hip_runtime.h>
#include <hip/hip_bf16.h>

// Problem: pooled = tanh(hs @ W^T + b); out0 = pooled[:,0]; out1 = span-means;
// out2 = zeros(N,S).  N=64, L=512, H=768, S=16. Inputs fp32, d_out fp32.
//
// R7 = R6 with the compile fix: LDS buffer pointers computed by offset
// arithmetic per use (a `const` array of LDS pointers forced an addrspacecast
// static initializer -> gfx950 codegen error).
// Structure: atomic-free; one block = one FULL passage (BM=512) x 64 cols;
// spans reduced in-LDS, direct stores (R5: 8.2M atomics = 33MB RMW traffic).
#define NPASS 64
#define LSEQ  512
#define HDIM  768
#define NSPAN 16
#define MTOT  (NPASS*LSEQ)                     // 32768
#define OFF_SENT (NPASS*HDIM)                  // 49152
#define A_ELEMS (MTOT*HDIM)                    // 25165824
#define W_ELEMS (HDIM*HDIM)                    // 589824

#define BM 512
#define BN 64
#define BK 32
#define NK (HDIM/BK)                           // 24 K-iterations
#define NBLK (HDIM/BN)                         // 12 N-blocks per passage

typedef __bf16 bf16x8 __attribute__((ext_vector_type(8)));
typedef float  f32x4  __attribute__((ext_vector_type(4)));

__device__ inline unsigned short f2bf(float f) {
  __hip_bfloat16 h = __float2bfloat16(f);   // RNE
  unsigned short u; __builtin_memcpy(&u, &h, 2); return u;
}

// tanh via v_exp_f32 (~7 VALU vs ~25 libm). |err|<1e-6, threshold is 2e-2.
__device__ inline float fast_tanh(float x) {
  const float ax = fabsf(x);
  const float t  = __expf(-2.0f * ax);
  const float r  = (1.0f - t) * __builtin_amdgcn_rcpf(1.0f + t);
  return copysignf(r, x);
}

// fp32 -> bf16 one-shot convert of A then W. 8 elems/thread, 16B stores.
__global__ __launch_bounds__(256) void convert_kernel(
    const float* __restrict__ A, const float* __restrict__ W,
    unsigned short* __restrict__ Ab, unsigned short* __restrict__ Wb)
{
  const long long i = ((long long)blockIdx.x * 256 + threadIdx.x) * 8;
  const float* src; unsigned short* dst; long long off;
  if (i < A_ELEMS) { src = A; dst = Ab; off = i; }
  else             { src = W; dst = Wb; off = i - A_ELEMS; }
  const float4 a = *(const float4*)(src + off);
  const float4 b = *(const float4*)(src + off + 4);
  union { unsigned short us[8]; uint4 v; } o;
  o.us[0]=f2bf(a.x); o.us[1]=f2bf(a.y); o.us[2]=f2bf(a.z); o.us[3]=f2bf(a.w);
  o.us[4]=f2bf(b.x); o.us[5]=f2bf(b.y); o.us[6]=f2bf(b.z); o.us[7]=f2bf(b.w);
  *(uint4*)(dst + off) = o.v;
}

// bf16 NT GEMM, one passage per block, fused tanh + span-mean epilogue.
// 512 threads = 8 waves; wave w owns rows [64w, 64w+64) x all 64 block cols.
__global__ __launch_bounds__(512, 4) void gemm_fused_kernel(
    const unsigned short* __restrict__ Ab,
    const unsigned short* __restrict__ Wb,
    const float* __restrict__ bias,
    const int* __restrict__ spans,
    float* __restrict__ out)
{
  // Manual pool: As dbuf 2x32KB @0, Bs dbuf 2x4KB @65536 = 72KB. The 512x16
  // fp32 epilogue strip (32KB) aliases As[0] (dead after last K barrier).
  __shared__ __align__(16) unsigned char smem[73728];
  __shared__ int   sp_st[NSPAN], sp_en[NSPAN];
  __shared__ float inv_s[NSPAN];
  __shared__ float bias_s[BN];

  const int tid  = threadIdx.x;
  const int wave = tid >> 6;        // 0..7
  const int lane = tid & 63;
  const int quad = lane >> 4;
  const int lr   = lane & 15;

  // Swizzle: all 12 N-blocks of a passage share b%8 -> same XCD.
  const int b     = blockIdx.x;            // 0..767
  const int rest  = b >> 3;                // 0..95
  const int npass = (rest / NBLK) * 8 + (b & 7);
  const int nb    = rest % NBLK;
  const int tile_n = nb * BN;
  const size_t arow0 = (size_t)npass * LSEQ;

  // global_load_lds: lane i -> ldsbase + i*16B. Row-major [rows][32] bf16,
  // 64B/row: 1KB segment = 16 rows; lane -> row lane/4, col (lane%4)*8.
  const int lrow = lane >> 2;
  const int lcol = (lane & 3) * 8;

  auto stage = [&](int k, int buf) {
    const int k0 = k * BK;
    unsigned short* As = (unsigned short*)(smem + buf * 32768);
    unsigned short* Bs = (unsigned short*)(smem + 65536 + buf * 4096);
    #pragma unroll
    for (int j = 0; j < 4; ++j) {
      const int seg = wave + j * 8;        // 0..31, wave-uniform
      const unsigned short* g =
          Ab + (arow0 + seg * 16 + lrow) * HDIM + (k0 + lcol);
      __builtin_amdgcn_global_load_lds(
          (const __attribute__((address_space(1))) void*)g,
          (__attribute__((address_space(3))) void*)(As + seg * 512),
          16, 0, 0);
    }
    if (wave < 4) {                        // B: 64 rows = 4 segments
      const unsigned short* g =
          Wb + (size_t)(tile_n + wave * 16 + lrow) * HDIM + (k0 + lcol);
      __builtin_amdgcn_global_load_lds(
          (const __attribute__((address_space(1))) void*)g,
          (__attribute__((address_space(3))) void*)(Bs + wave * 512),
          16, 0, 0);
    }
  };

  // Prologue: stage slice 0 + tables, one barrier.
  stage(0, 0);
  if (tid < NSPAN) {
    const int st = spans[(npass * NSPAN + tid) * 2 + 0];
    const int en = spans[(npass * NSPAN + tid) * 2 + 1];
    sp_st[tid] = st; sp_en[tid] = en; inv_s[tid] = 1.0f / (float)(en - st);
  }
  if (tid >= 128 && tid < 128 + BN) bias_s[tid - 128] = bias[tile_n + tid - 128];
  __syncthreads();

  f32x4 acc[4][4];   // [mt rows][nt cols]
  #pragma unroll
  for (int i = 0; i < 4; ++i)
    #pragma unroll
    for (int j = 0; j < 4; ++j)
      acc[i][j] = (f32x4){0.f, 0.f, 0.f, 0.f};

  for (int k = 0; k < NK; ++k) {
    const int cur = k & 1;
    if (k + 1 < NK) stage(k + 1, cur ^ 1);   // prefetch-distance-1

    const unsigned short* As = (const unsigned short*)(smem + cur * 32768);
    const unsigned short* Bs = (const unsigned short*)(smem + 65536 + cur * 4096);

    // A-frag A[m=lane&15][k=quad*8+j]; B-frag B[k][n=lane&15] (W row = B col).
    bf16x8 af[4], bf[4];
    #pragma unroll
    for (int mt = 0; mt < 4; ++mt)
      af[mt] = *(const bf16x8*)(As + ((wave * 64 + mt * 16 + lr) * BK + quad * 8));
    #pragma unroll
    for (int nt = 0; nt < 4; ++nt)
      bf[nt] = *(const bf16x8*)(Bs + ((nt * 16 + lr) * BK + quad * 8));

    #pragma unroll
    for (int mt = 0; mt < 4; ++mt)
      #pragma unroll
      for (int nt = 0; nt < 4; ++nt)
        acc[mt][nt] = __builtin_amdgcn_mfma_f32_16x16x32_bf16(
            af[mt], bf[nt], acc[mt][nt], 0, 0, 0);

    __syncthreads();
  }

  // Epilogue: 4 strips of 16 cols. C/D layout col=lane&15, row=quad*4+reg
  // (R3/R4/R5-validated). Strip (aliases As[0]) holds the full 512-row column
  // group; spans reduced in-LDS; direct stores, no atomics.
  float* strip = (float*)smem;   // [512][16] fp32
  #pragma unroll 1
  for (int nt = 0; nt < 4; ++nt) {
    const float bv = bias_s[nt * 16 + lr];
    #pragma unroll
    for (int mt = 0; mt < 4; ++mt)
      #pragma unroll
      for (int r = 0; r < 4; ++r) {
        const int row = wave * 64 + mt * 16 + quad * 4 + r;
        strip[row * 16 + lr] = fast_tanh(acc[mt][nt][r] + bv);
      }
    __syncthreads();
    if (tid < 256) {
      const int s = tid >> 4, c = tid & 15;
      float sum = 0.f;
      for (int l = sp_st[s]; l < sp_en[s]; ++l) sum += strip[l * 16 + c];
      out[OFF_SENT + (size_t)(npass * NSPAN + s) * HDIM + tile_n + nt * 16 + c]
          = sum * inv_s[s];
    } else if (tid < 272) {
      const int c = tid - 256;   // passage row 0 (local row 0 of this block)
      out[(size_t)npass * HDIM + tile_n + nt * 16 + c] = strip[c];
    }
    __syncthreads();
  }
}

extern "C" void kernel_launch(void* const* d_in, const int* in_sizes, int n_in,
                              void* d_out, int out_size, void* d_ws, size_t ws_size,
                              hipStream_t stream) {
  const float* hs  = (const float*)d_in[0];  // (64,512,768) fp32
  const float* w   = (const float*)d_in[1];  // (768,768) fp32
  const float* bsc = (const float*)d_in[2];  // (768,) fp32
  // d_in[3] attention_mask unused
  const int* spans = (const int*)d_in[4];    // (64,16,2) int32
  float* out = (float*)d_out;

  unsigned short* Ab = (unsigned short*)d_ws;            // 50,331,648 B
  unsigned short* Wb = Ab + A_ELEMS;                     // +1,179,648 B

  // Zeroes the sentence_mask region (rest of out is fully overwritten).
  (void)hipMemsetAsync(d_out, 0, (size_t)out_size * sizeof(float), stream);

  convert_kernel<<<dim3((A_ELEMS + W_ELEMS) / 8 / 256), dim3(256), 0, stream>>>(
      hs, w, Ab, Wb);

  gemm_fused_kernel<<<dim3(NPASS * NBLK), dim3(512), 0, stream>>>(
      Ab, Wb, bsc, spans, out);
}

// Round 8
// 542.380 us; speedup vs baseline: 1.0014x; 1.0014x over previous
//
#include <hip/hip_runtime.h>
#include <hip/hip_bf16.h>

// Problem: pooled = tanh(hs @ W^T + b); out0 = pooled[:,0]; out1 = span-means;
// out2 = zeros(N,S).  N=64, L=512, H=768, S=16. Inputs fp32, d_out fp32.
//
// R8 = R7 with the spill fix. R7's __launch_bounds__(512,4) meant min 4
// waves/EU -> VGPR cap 128 -> accumulator spilled to scratch (VGPR_Count=56,
// WRITE_SIZE=2.37GB == 24 iters x 256B x 512thr x 768blk of acc spills,
// HBM 81% busy on spill traffic). (512,2) -> cap 256, no spill.
// Structure: atomic-free; one block = one FULL passage (BM=512) x 64 cols;
// spans reduced in-LDS, direct stores; XCD-swizzled grid; LDS dbuf prefetch.
#define NPASS 64
#define LSEQ  512
#define HDIM  768
#define NSPAN 16
#define MTOT  (NPASS*LSEQ)                     // 32768
#define OFF_SENT (NPASS*HDIM)                  // 49152
#define A_ELEMS (MTOT*HDIM)                    // 25165824
#define W_ELEMS (HDIM*HDIM)                    // 589824

#define BM 512
#define BN 64
#define BK 32
#define NK (HDIM/BK)                           // 24 K-iterations
#define NBLK (HDIM/BN)                         // 12 N-blocks per passage

typedef __bf16 bf16x8 __attribute__((ext_vector_type(8)));
typedef float  f32x4  __attribute__((ext_vector_type(4)));

__device__ inline unsigned short f2bf(float f) {
  __hip_bfloat16 h = __float2bfloat16(f);   // RNE
  unsigned short u; __builtin_memcpy(&u, &h, 2); return u;
}

// tanh via v_exp_f32 (~7 VALU vs ~25 libm). |err|<1e-6, threshold is 2e-2.
__device__ inline float fast_tanh(float x) {
  const float ax = fabsf(x);
  const float t  = __expf(-2.0f * ax);
  const float r  = (1.0f - t) * __builtin_amdgcn_rcpf(1.0f + t);
  return copysignf(r, x);
}

// fp32 -> bf16 one-shot convert of A then W. 8 elems/thread, 16B stores.
__global__ __launch_bounds__(256) void convert_kernel(
    const float* __restrict__ A, const float* __restrict__ W,
    unsigned short* __restrict__ Ab, unsigned short* __restrict__ Wb)
{
  const long long i = ((long long)blockIdx.x * 256 + threadIdx.x) * 8;
  const float* src; unsigned short* dst; long long off;
  if (i < A_ELEMS) { src = A; dst = Ab; off = i; }
  else             { src = W; dst = Wb; off = i - A_ELEMS; }
  const float4 a = *(const float4*)(src + off);
  const float4 b = *(const float4*)(src + off + 4);
  union { unsigned short us[8]; uint4 v; } o;
  o.us[0]=f2bf(a.x); o.us[1]=f2bf(a.y); o.us[2]=f2bf(a.z); o.us[3]=f2bf(a.w);
  o.us[4]=f2bf(b.x); o.us[5]=f2bf(b.y); o.us[6]=f2bf(b.z); o.us[7]=f2bf(b.w);
  *(uint4*)(dst + off) = o.v;
}

// bf16 NT GEMM, one passage per block, fused tanh + span-mean epilogue.
// 512 threads = 8 waves; wave w owns rows [64w, 64w+64) x all 64 block cols.
// launch_bounds (512, 2): VGPR cap 256 — acc[4][4] (64 regs) + frags must NOT
// spill (R7 post-mortem).
__global__ __launch_bounds__(512, 2) void gemm_fused_kernel(
    const unsigned short* __restrict__ Ab,
    const unsigned short* __restrict__ Wb,
    const float* __restrict__ bias,
    const int* __restrict__ spans,
    float* __restrict__ out)
{
  // Manual pool: As dbuf 2x32KB @0, Bs dbuf 2x4KB @65536 = 72KB. The 512x16
  // fp32 epilogue strip (32KB) aliases As[0] (dead after last K barrier).
  __shared__ __align__(16) unsigned char smem[73728];
  __shared__ int   sp_st[NSPAN], sp_en[NSPAN];
  __shared__ float inv_s[NSPAN];
  __shared__ float bias_s[BN];

  const int tid  = threadIdx.x;
  const int wave = tid >> 6;        // 0..7
  const int lane = tid & 63;
  const int quad = lane >> 4;
  const int lr   = lane & 15;

  // Swizzle: all 12 N-blocks of a passage share b%8 -> same XCD.
  const int b     = blockIdx.x;            // 0..767
  const int rest  = b >> 3;                // 0..95
  const int npass = (rest / NBLK) * 8 + (b & 7);
  const int nb    = rest % NBLK;
  const int tile_n = nb * BN;
  const size_t arow0 = (size_t)npass * LSEQ;

  // global_load_lds: lane i -> ldsbase + i*16B. Row-major [rows][32] bf16,
  // 64B/row: 1KB segment = 16 rows; lane -> row lane/4, col (lane%4)*8.
  const int lrow = lane >> 2;
  const int lcol = (lane & 3) * 8;

  auto stage = [&](int k, int buf) {
    const int k0 = k * BK;
    unsigned short* As = (unsigned short*)(smem + buf * 32768);
    unsigned short* Bs = (unsigned short*)(smem + 65536 + buf * 4096);
    #pragma unroll
    for (int j = 0; j < 4; ++j) {
      const int seg = wave + j * 8;        // 0..31, wave-uniform
      const unsigned short* g =
          Ab + (arow0 + seg * 16 + lrow) * HDIM + (k0 + lcol);
      __builtin_amdgcn_global_load_lds(
          (const __attribute__((address_space(1))) void*)g,
          (__attribute__((address_space(3))) void*)(As + seg * 512),
          16, 0, 0);
    }
    if (wave < 4) {                        // B: 64 rows = 4 segments
      const unsigned short* g =
          Wb + (size_t)(tile_n + wave * 16 + lrow) * HDIM + (k0 + lcol);
      __builtin_amdgcn_global_load_lds(
          (const __attribute__((address_space(1))) void*)g,
          (__attribute__((address_space(3))) void*)(Bs + wave * 512),
          16, 0, 0);
    }
  };

  // Prologue: stage slice 0 + tables, one barrier.
  stage(0, 0);
  if (tid < NSPAN) {
    const int st = spans[(npass * NSPAN + tid) * 2 + 0];
    const int en = spans[(npass * NSPAN + tid) * 2 + 1];
    sp_st[tid] = st; sp_en[tid] = en; inv_s[tid] = 1.0f / (float)(en - st);
  }
  if (tid >= 128 && tid < 128 + BN) bias_s[tid - 128] = bias[tile_n + tid - 128];
  __syncthreads();

  f32x4 acc[4][4];   // [mt rows][nt cols]
  #pragma unroll
  for (int i = 0; i < 4; ++i)
    #pragma unroll
    for (int j = 0; j < 4; ++j)
      acc[i][j] = (f32x4){0.f, 0.f, 0.f, 0.f};

  for (int k = 0; k < NK; ++k) {
    const int cur = k & 1;
    if (k + 1 < NK) stage(k + 1, cur ^ 1);   // prefetch-distance-1

    const unsigned short* As = (const unsigned short*)(smem + cur * 32768);
    const unsigned short* Bs = (const unsigned short*)(smem + 65536 + cur * 4096);

    // A-frag A[m=lane&15][k=quad*8+j]; B-frag B[k][n=lane&15] (W row = B col).
    bf16x8 af[4], bf[4];
    #pragma unroll
    for (int mt = 0; mt < 4; ++mt)
      af[mt] = *(const bf16x8*)(As + ((wave * 64 + mt * 16 + lr) * BK + quad * 8));
    #pragma unroll
    for (int nt = 0; nt < 4; ++nt)
      bf[nt] = *(const bf16x8*)(Bs + ((nt * 16 + lr) * BK + quad * 8));

    #pragma unroll
    for (int mt = 0; mt < 4; ++mt)
      #pragma unroll
      for (int nt = 0; nt < 4; ++nt)
        acc[mt][nt] = __builtin_amdgcn_mfma_f32_16x16x32_bf16(
            af[mt], bf[nt], acc[mt][nt], 0, 0, 0);

    __syncthreads();
  }

  // Epilogue: 4 strips of 16 cols. C/D layout col=lane&15, row=quad*4+reg
  // (R3/R4/R5-validated). Strip (aliases As[0]) holds the full 512-row column
  // group; spans reduced in-LDS; direct stores, no atomics.
  float* strip = (float*)smem;   // [512][16] fp32
  #pragma unroll 1
  for (int nt = 0; nt < 4; ++nt) {
    const float bv = bias_s[nt * 16 + lr];
    #pragma unroll
    for (int mt = 0; mt < 4; ++mt)
      #pragma unroll
      for (int r = 0; r < 4; ++r) {
        const int row = wave * 64 + mt * 16 + quad * 4 + r;
        strip[row * 16 + lr] = fast_tanh(acc[mt][nt][r] + bv);
      }
    __syncthreads();
    if (tid < 256) {
      const int s = tid >> 4, c = tid & 15;
      float sum = 0.f;
      for (int l = sp_st[s]; l < sp_en[s]; ++l) sum += strip[l * 16 + c];
      out[OFF_SENT + (size_t)(npass * NSPAN + s) * HDIM + tile_n + nt * 16 + c]
          = sum * inv_s[s];
    } else if (tid < 272) {
      const int c = tid - 256;   // passage row 0 (local row 0 of this block)
      out[(size_t)npass * HDIM + tile_n + nt * 16 + c] = strip[c];
    }
    __syncthreads();
  }
}

extern "C" void kernel_launch(void* const* d_in, const int* in_sizes, int n_in,
                              void* d_out, int out_size, void* d_ws, size_t ws_size,
                              hipStream_t stream) {
  const float* hs  = (const float*)d_in[0];  // (64,512,768) fp32
  const float* w   = (const float*)d_in[1];  // (768,768) fp32
  const float* bsc = (const float*)d_in[2];  // (768,) fp32
  // d_in[3] attention_mask unused
  const int* spans = (const int*)d_in[4];    // (64,16,2) int32
  float* out = (float*)d_out;

  unsigned short* Ab = (unsigned short*)d_ws;            // 50,331,648 B
  unsigned short* Wb = Ab + A_ELEMS;                     // +1,179,648 B

  // Zeroes the sentence_mask region (rest of out is fully overwritten).
  (void)hipMemsetAsync(d_out, 0, (size_t)out_size * sizeof(float), stream);

  convert_kernel<<<dim3((A_ELEMS + W_ELEMS) / 8 / 256), dim3(256), 0, stream>>>(
      hs, w, Ab, Wb);

  gemm_fused_kernel<<<dim3(NPASS * NBLK), dim3(512), 0, stream>>>(
      Ab, Wb, bsc, spans, out);
}

// Round 9
// 281.698 us; speedup vs baseline: 1.9281x; 1.9254x over previous
//
#include <hip/hip_runtime.h>
#include <hip/hip_bf16.h>

// Problem: pooled = tanh(hs @ W^T + b); out0 = pooled[:,0]; out1 = span-means;
// out2 = zeros(N,S).  N=64, L=512, H=768, S=16. Inputs fp32, d_out fp32.
//
// R9 = R8 with the REAL spill fix. R7/R8's epilogue had `#pragma unroll 1`
// on the nt loop -> acc[mt][nt] dynamically indexed -> whole acc[4][4]
// demoted to scratch for the entire kernel (VGPR_Count=56, WRITE_SIZE=2.4GB
// = 24 iters x 256B x 512thr x 768blk of acc round-trips; launch_bounds had
// no effect because the spill was code-forced, not budget-forced).
// Fix: fully unroll the epilogue so all acc indices are constants.
// Structure: atomic-free; one block = one FULL passage (BM=512) x 64 cols;
// spans reduced in-LDS, direct stores; XCD-swizzled grid; LDS dbuf prefetch.
#define NPASS 64
#define LSEQ  512
#define HDIM  768
#define NSPAN 16
#define MTOT  (NPASS*LSEQ)                     // 32768
#define OFF_SENT (NPASS*HDIM)                  // 49152
#define A_ELEMS (MTOT*HDIM)                    // 25165824
#define W_ELEMS (HDIM*HDIM)                    // 589824

#define BM 512
#define BN 64
#define BK 32
#define NK (HDIM/BK)                           // 24 K-iterations
#define NBLK (HDIM/BN)                         // 12 N-blocks per passage

typedef __bf16 bf16x8 __attribute__((ext_vector_type(8)));
typedef float  f32x4  __attribute__((ext_vector_type(4)));

__device__ inline unsigned short f2bf(float f) {
  __hip_bfloat16 h = __float2bfloat16(f);   // RNE
  unsigned short u; __builtin_memcpy(&u, &h, 2); return u;
}

// tanh via v_exp_f32 (~7 VALU vs ~25 libm). |err|<1e-6, threshold is 2e-2.
__device__ inline float fast_tanh(float x) {
  const float ax = fabsf(x);
  const float t  = __expf(-2.0f * ax);
  const float r  = (1.0f - t) * __builtin_amdgcn_rcpf(1.0f + t);
  return copysignf(r, x);
}

// fp32 -> bf16 one-shot convert of A then W. 8 elems/thread, 16B stores.
__global__ __launch_bounds__(256) void convert_kernel(
    const float* __restrict__ A, const float* __restrict__ W,
    unsigned short* __restrict__ Ab, unsigned short* __restrict__ Wb)
{
  const long long i = ((long long)blockIdx.x * 256 + threadIdx.x) * 8;
  const float* src; unsigned short* dst; long long off;
  if (i < A_ELEMS) { src = A; dst = Ab; off = i; }
  else             { src = W; dst = Wb; off = i - A_ELEMS; }
  const float4 a = *(const float4*)(src + off);
  const float4 b = *(const float4*)(src + off + 4);
  union { unsigned short us[8]; uint4 v; } o;
  o.us[0]=f2bf(a.x); o.us[1]=f2bf(a.y); o.us[2]=f2bf(a.z); o.us[3]=f2bf(a.w);
  o.us[4]=f2bf(b.x); o.us[5]=f2bf(b.y); o.us[6]=f2bf(b.z); o.us[7]=f2bf(b.w);
  *(uint4*)(dst + off) = o.v;
}

// bf16 NT GEMM, one passage per block, fused tanh + span-mean epilogue.
// 512 threads = 8 waves; wave w owns rows [64w, 64w+64) x all 64 block cols.
__global__ __launch_bounds__(512, 2) void gemm_fused_kernel(
    const unsigned short* __restrict__ Ab,
    const unsigned short* __restrict__ Wb,
    const float* __restrict__ bias,
    const int* __restrict__ spans,
    float* __restrict__ out)
{
  // Manual pool: As dbuf 2x32KB @0, Bs dbuf 2x4KB @65536 = 72KB. The 512x16
  // fp32 epilogue strip (32KB) aliases As[0] (dead after last K barrier).
  __shared__ __align__(16) unsigned char smem[73728];
  __shared__ int   sp_st[NSPAN], sp_en[NSPAN];
  __shared__ float inv_s[NSPAN];
  __shared__ float bias_s[BN];

  const int tid  = threadIdx.x;
  const int wave = tid >> 6;        // 0..7
  const int lane = tid & 63;
  const int quad = lane >> 4;
  const int lr   = lane & 15;

  // Swizzle: all 12 N-blocks of a passage share b%8 -> same XCD.
  const int b     = blockIdx.x;            // 0..767
  const int rest  = b >> 3;                // 0..95
  const int npass = (rest / NBLK) * 8 + (b & 7);
  const int nb    = rest % NBLK;
  const int tile_n = nb * BN;
  const size_t arow0 = (size_t)npass * LSEQ;

  // global_load_lds: lane i -> ldsbase + i*16B. Row-major [rows][32] bf16,
  // 64B/row: 1KB segment = 16 rows; lane -> row lane/4, col (lane%4)*8.
  const int lrow = lane >> 2;
  const int lcol = (lane & 3) * 8;

  auto stage = [&](int k, int buf) {
    const int k0 = k * BK;
    unsigned short* As = (unsigned short*)(smem + buf * 32768);
    unsigned short* Bs = (unsigned short*)(smem + 65536 + buf * 4096);
    #pragma unroll
    for (int j = 0; j < 4; ++j) {
      const int seg = wave + j * 8;        // 0..31, wave-uniform
      const unsigned short* g =
          Ab + (arow0 + seg * 16 + lrow) * HDIM + (k0 + lcol);
      __builtin_amdgcn_global_load_lds(
          (const __attribute__((address_space(1))) void*)g,
          (__attribute__((address_space(3))) void*)(As + seg * 512),
          16, 0, 0);
    }
    if (wave < 4) {                        // B: 64 rows = 4 segments
      const unsigned short* g =
          Wb + (size_t)(tile_n + wave * 16 + lrow) * HDIM + (k0 + lcol);
      __builtin_amdgcn_global_load_lds(
          (const __attribute__((address_space(1))) void*)g,
          (__attribute__((address_space(3))) void*)(Bs + wave * 512),
          16, 0, 0);
    }
  };

  // Prologue: stage slice 0 + tables, one barrier.
  stage(0, 0);
  if (tid < NSPAN) {
    const int st = spans[(npass * NSPAN + tid) * 2 + 0];
    const int en = spans[(npass * NSPAN + tid) * 2 + 1];
    sp_st[tid] = st; sp_en[tid] = en; inv_s[tid] = 1.0f / (float)(en - st);
  }
  if (tid >= 128 && tid < 128 + BN) bias_s[tid - 128] = bias[tile_n + tid - 128];
  __syncthreads();

  f32x4 acc[4][4];   // [mt rows][nt cols] — must stay in registers!
  #pragma unroll
  for (int i = 0; i < 4; ++i)
    #pragma unroll
    for (int j = 0; j < 4; ++j)
      acc[i][j] = (f32x4){0.f, 0.f, 0.f, 0.f};

  for (int k = 0; k < NK; ++k) {
    const int cur = k & 1;
    if (k + 1 < NK) stage(k + 1, cur ^ 1);   // prefetch-distance-1

    const unsigned short* As = (const unsigned short*)(smem + cur * 32768);
    const unsigned short* Bs = (const unsigned short*)(smem + 65536 + cur * 4096);

    // A-frag A[m=lane&15][k=quad*8+j]; B-frag B[k][n=lane&15] (W row = B col).
    bf16x8 af[4], bf[4];
    #pragma unroll
    for (int mt = 0; mt < 4; ++mt)
      af[mt] = *(const bf16x8*)(As + ((wave * 64 + mt * 16 + lr) * BK + quad * 8));
    #pragma unroll
    for (int nt = 0; nt < 4; ++nt)
      bf[nt] = *(const bf16x8*)(Bs + ((nt * 16 + lr) * BK + quad * 8));

    #pragma unroll
    for (int mt = 0; mt < 4; ++mt)
      #pragma unroll
      for (int nt = 0; nt < 4; ++nt)
        acc[mt][nt] = __builtin_amdgcn_mfma_f32_16x16x32_bf16(
            af[mt], bf[nt], acc[mt][nt], 0, 0, 0);

    __syncthreads();
  }

  // Epilogue: 4 strips of 16 cols — FULLY UNROLLED so acc indices are
  // compile-time constants (dynamic nt indexing demotes acc to scratch:
  // R7/R8's 2.4GB WRITE_SIZE). C/D layout col=lane&15, row=quad*4+reg.
  float* strip = (float*)smem;   // [512][16] fp32, aliases As[0]
  #pragma unroll
  for (int nt = 0; nt < 4; ++nt) {
    const float bv = bias_s[nt * 16 + lr];
    #pragma unroll
    for (int mt = 0; mt < 4; ++mt)
      #pragma unroll
      for (int r = 0; r < 4; ++r) {
        const int row = wave * 64 + mt * 16 + quad * 4 + r;
        strip[row * 16 + lr] = fast_tanh(acc[mt][nt][r] + bv);
      }
    __syncthreads();
    if (tid < 256) {
      const int s = tid >> 4, c = tid & 15;
      float sum = 0.f;
      for (int l = sp_st[s]; l < sp_en[s]; ++l) sum += strip[l * 16 + c];
      out[OFF_SENT + (size_t)(npass * NSPAN + s) * HDIM + tile_n + nt * 16 + c]
          = sum * inv_s[s];
    } else if (tid < 272) {
      const int c = tid - 256;   // passage row 0 (local row 0 of this block)
      out[(size_t)npass * HDIM + tile_n + nt * 16 + c] = strip[c];
    }
    __syncthreads();
  }
}

extern "C" void kernel_launch(void* const* d_in, const int* in_sizes, int n_in,
                              void* d_out, int out_size, void* d_ws, size_t ws_size,
                              hipStream_t stream) {
  const float* hs  = (const float*)d_in[0];  // (64,512,768) fp32
  const float* w   = (const float*)d_in[1];  // (768,768) fp32
  const float* bsc = (const float*)d_in[2];  // (768,) fp32
  // d_in[3] attention_mask unused
  const int* spans = (const int*)d_in[4];    // (64,16,2) int32
  float* out = (float*)d_out;

  unsigned short* Ab = (unsigned short*)d_ws;            // 50,331,648 B
  unsigned short* Wb = Ab + A_ELEMS;                     // +1,179,648 B

  // Zeroes the sentence_mask region (rest of out is fully overwritten).
  (void)hipMemsetAsync(d_out, 0, (size_t)out_size * sizeof(float), stream);

  convert_kernel<<<dim3((A_ELEMS + W_ELEMS) / 8 / 256), dim3(256), 0, stream>>>(
      hs, w, Ab, Wb);

  gemm_fused_kernel<<<dim3(NPASS * NBLK), dim3(512), 0, stream>>>(
      Ab, Wb, bsc, spans, out);
}

// Round 10
// 272.476 us; speedup vs baseline: 1.9934x; 1.0338x over previous
//
#include <hip/hip_runtime.h>
#include <hip/hip_bf16.h>

// Problem: pooled = tanh(hs @ W^T + b); out0 = pooled[:,0]; out1 = span-means;
// out2 = zeros(N,S).  N=64, L=512, H=768, S=16. Inputs fp32, d_out fp32.
//
// R10: staged-bytes experiment. R3/R4/R5/R9 all pinned at ~125us while
// staging ~650MB through LDS at ~5TB/s (L3-sourced gathers) -> hypothesis:
// GEMM is staged-byte-bound, not latency/barrier-bound. This round: 256x256
// tiles cut staging to ~300MB (A x3 instead of x6/x12); XCD swizzle makes the
// 3 N-blocks of an M-row co-XCD so A-panel lives in that XCD's L2.
// Epilogue: R4-validated run-merged pre-scaled atomics (spans straddle the
// 256-row tile boundary). acc 8x4 frags = 128 VGPR; launch_bounds(512,1),
// fully-unrolled epilogue (R9 lesson: dynamic acc indexing = scratch demotion).
#define NPASS 64
#define LSEQ  512
#define HDIM  768
#define NSPAN 16
#define MTOT  (NPASS*LSEQ)                     // 32768
#define OFF_SENT (NPASS*HDIM)                  // 49152
#define A_ELEMS (MTOT*HDIM)                    // 25165824
#define W_ELEMS (HDIM*HDIM)                    // 589824

#define BM 256
#define BN 256
#define BK 32
#define NK (HDIM/BK)                           // 24 K-iterations
#define MT_M (MTOT/BM)                         // 128 m-tiles
#define MT_N (HDIM/BN)                         // 3 n-tiles

typedef __bf16 bf16x8 __attribute__((ext_vector_type(8)));
typedef float  f32x4  __attribute__((ext_vector_type(4)));

__device__ inline unsigned short f2bf(float f) {
  __hip_bfloat16 h = __float2bfloat16(f);   // RNE
  unsigned short u; __builtin_memcpy(&u, &h, 2); return u;
}

// tanh via v_exp_f32 (~7 VALU vs ~25 libm). |err|<1e-6, threshold is 2e-2.
__device__ inline float fast_tanh(float x) {
  const float ax = fabsf(x);
  const float t  = __expf(-2.0f * ax);
  const float r  = (1.0f - t) * __builtin_amdgcn_rcpf(1.0f + t);
  return copysignf(r, x);
}

// fp32 -> bf16 one-shot convert of A then W. 8 elems/thread, 16B stores.
__global__ __launch_bounds__(256) void convert_kernel(
    const float* __restrict__ A, const float* __restrict__ W,
    unsigned short* __restrict__ Ab, unsigned short* __restrict__ Wb)
{
  const long long i = ((long long)blockIdx.x * 256 + threadIdx.x) * 8;
  const float* src; unsigned short* dst; long long off;
  if (i < A_ELEMS) { src = A; dst = Ab; off = i; }
  else             { src = W; dst = Wb; off = i - A_ELEMS; }
  const float4 a = *(const float4*)(src + off);
  const float4 b = *(const float4*)(src + off + 4);
  union { unsigned short us[8]; uint4 v; } o;
  o.us[0]=f2bf(a.x); o.us[1]=f2bf(a.y); o.us[2]=f2bf(a.z); o.us[3]=f2bf(a.w);
  o.us[4]=f2bf(b.x); o.us[5]=f2bf(b.y); o.us[6]=f2bf(b.z); o.us[7]=f2bf(b.w);
  *(uint4*)(dst + off) = o.v;
}

// bf16 NT GEMM, 256x256 tile, 512 threads = 8 waves (wave grid 2m x 4n:
// wave owns 128 rows x 64 cols = 8mt x 4nt 16x16 frags). Fused tanh + pool.
__global__ __launch_bounds__(512, 1) void gemm_fused_kernel(
    const unsigned short* __restrict__ Ab,
    const unsigned short* __restrict__ Wb,
    const float* __restrict__ bias,
    const int* __restrict__ spans,
    float* __restrict__ out)
{
  // As dbuf 2x16KB @0, Bs dbuf 2x16KB @32768 -> 64KB.
  __shared__ __align__(16) unsigned char smem[65536];
  __shared__ int   sp_st[NSPAN], sp_en[NSPAN];
  __shared__ float inv_s[NSPAN];
  __shared__ short sid_l[BM];      // local row -> span id (-1 none)
  __shared__ float bias_s[BN];

  const int tid  = threadIdx.x;
  const int wave = tid >> 6;        // 0..7
  const int lane = tid & 63;
  const int quad = lane >> 4;
  const int lr   = lane & 15;
  const int wm   = wave >> 2;       // 0..1 (row half)
  const int wn   = wave & 3;        // 0..3 (col quarter)

  // Swizzle: the 3 N-blocks of an m-row share b&7 -> same XCD (A in its L2).
  const int b    = blockIdx.x;             // 0..383
  const int rest = b >> 3;                 // 0..47
  const int mrow = (rest / MT_N) * 8 + (b & 7);   // 0..127
  const int nb   = rest % MT_N;            // 0..2
  const int tile_m = mrow * BM;
  const int tile_n = nb * BN;
  const int npass  = tile_m >> 9;          // passage index (BM=256 divides 512)
  const int l0     = tile_m & 511;         // 0 or 256
  const size_t arow0 = (size_t)tile_m;

  // global_load_lds: lane i -> ldsbase + i*16B. Row-major [256][32] bf16,
  // 64B/row: 1KB segment = 16 rows; lane -> row lane/4, col (lane%4)*8.
  const int lrow = lane >> 2;
  const int lcol = (lane & 3) * 8;

  auto stage = [&](int k, int buf) {
    const int k0 = k * BK;
    unsigned short* As = (unsigned short*)(smem + buf * 16384);
    unsigned short* Bs = (unsigned short*)(smem + 32768 + buf * 16384);
    #pragma unroll
    for (int j = 0; j < 4; ++j) {
      const int seg = wave + j * 8;        // 0..31, wave-uniform
      if (seg < 16) {
        const unsigned short* g =
            Ab + (arow0 + seg * 16 + lrow) * HDIM + (k0 + lcol);
        __builtin_amdgcn_global_load_lds(
            (const __attribute__((address_space(1))) void*)g,
            (__attribute__((address_space(3))) void*)(As + seg * 512),
            16, 0, 0);
      } else {
        const int s2 = seg - 16;
        const unsigned short* g =
            Wb + (size_t)(tile_n + s2 * 16 + lrow) * HDIM + (k0 + lcol);
        __builtin_amdgcn_global_load_lds(
            (const __attribute__((address_space(1))) void*)g,
            (__attribute__((address_space(3))) void*)(Bs + s2 * 512),
            16, 0, 0);
      }
    }
  };

  // Prologue: stage slice 0 + tables, one barrier.
  stage(0, 0);
  if (tid < NSPAN) {
    const int st = spans[(npass * NSPAN + tid) * 2 + 0];
    const int en = spans[(npass * NSPAN + tid) * 2 + 1];
    sp_st[tid] = st; sp_en[tid] = en; inv_s[tid] = 1.0f / (float)(en - st);
  }
  if (tid >= 256) bias_s[tid - 256] = bias[tile_n + tid - 256];
  __syncthreads();
  if (tid < BM) {   // written once, read only in epilogue (after barriers)
    const int l = l0 + tid;
    short s = -1;
    #pragma unroll
    for (int i = 0; i < NSPAN; ++i)
      if (l >= sp_st[i] && l < sp_en[i]) s = (short)i;
    sid_l[tid] = s;
  }

  f32x4 acc[8][4];   // [mt][nt] — must stay in registers (no dynamic idx!)
  #pragma unroll
  for (int i = 0; i < 8; ++i)
    #pragma unroll
    for (int j = 0; j < 4; ++j)
      acc[i][j] = (f32x4){0.f, 0.f, 0.f, 0.f};

  for (int k = 0; k < NK; ++k) {
    const int cur = k & 1;
    if (k + 1 < NK) stage(k + 1, cur ^ 1);   // prefetch-distance-1

    const unsigned short* As = (const unsigned short*)(smem + cur * 16384);
    const unsigned short* Bs = (const unsigned short*)(smem + 32768 + cur * 16384);

    // A-frag A[m=lane&15][k=quad*8+j]; B-frag B[k][n=lane&15] (W row = B col).
    bf16x8 af[8], bf[4];
    #pragma unroll
    for (int mt = 0; mt < 8; ++mt)
      af[mt] = *(const bf16x8*)(As + ((wm * 128 + mt * 16 + lr) * BK + quad * 8));
    #pragma unroll
    for (int nt = 0; nt < 4; ++nt)
      bf[nt] = *(const bf16x8*)(Bs + ((wn * 64 + nt * 16 + lr) * BK + quad * 8));

    #pragma unroll
    for (int mt = 0; mt < 8; ++mt)
      #pragma unroll
      for (int nt = 0; nt < 4; ++nt)
        acc[mt][nt] = __builtin_amdgcn_mfma_f32_16x16x32_bf16(
            af[mt], bf[nt], acc[mt][nt], 0, 0, 0);

    __syncthreads();
  }

  // Epilogue (fully unrolled; R4-validated structure). C/D layout:
  // col=lane&15, row=quad*4+reg. Run-merged pre-scaled atomics into
  // pre-zeroed out; direct store for passage row 0.
  #pragma unroll
  for (int nt = 0; nt < 4; ++nt) {
    const int lcolo = wn * 64 + nt * 16 + lr;       // 0..255
    const int col   = tile_n + lcolo;
    const float bv  = bias_s[lcolo];
    float* sent_col = out + OFF_SENT + (size_t)(npass * NSPAN) * HDIM + col;
    #pragma unroll
    for (int mt = 0; mt < 8; ++mt) {
      const int rowbase = wm * 128 + mt * 16 + quad * 4;  // local row
      int prev = -1; float run = 0.f;
      #pragma unroll
      for (int r = 0; r < 4; ++r) {
        const int lrw = rowbase + r;
        const float v = fast_tanh(acc[mt][nt][r] + bv);
        if (l0 == 0 && lrw == 0) out[(size_t)npass * HDIM + col] = v;
        const int s = sid_l[lrw];
        if (s != prev) {
          if (prev >= 0) unsafeAtomicAdd(sent_col + (size_t)prev * HDIM, run * inv_s[prev]);
          prev = s; run = 0.f;
        }
        run += v;
      }
      if (prev >= 0) unsafeAtomicAdd(sent_col + (size_t)prev * HDIM, run * inv_s[prev]);
    }
  }
}

extern "C" void kernel_launch(void* const* d_in, const int* in_sizes, int n_in,
                              void* d_out, int out_size, void* d_ws, size_t ws_size,
                              hipStream_t stream) {
  const float* hs  = (const float*)d_in[0];  // (64,512,768) fp32
  const float* w   = (const float*)d_in[1];  // (768,768) fp32
  const float* bsc = (const float*)d_in[2];  // (768,) fp32
  // d_in[3] attention_mask unused
  const int* spans = (const int*)d_in[4];    // (64,16,2) int32
  float* out = (float*)d_out;

  unsigned short* Ab = (unsigned short*)d_ws;            // 50,331,648 B
  unsigned short* Wb = Ab + A_ELEMS;                     // +1,179,648 B

  // Zero all outputs (sentence region is accumulated into; mask stays 0).
  (void)hipMemsetAsync(d_out, 0, (size_t)out_size * sizeof(float), stream);

  convert_kernel<<<dim3((A_ELEMS + W_ELEMS) / 8 / 256), dim3(256), 0, stream>>>(
      hs, w, Ab, Wb);

  gemm_fused_kernel<<<dim3(MT_M * MT_N), dim3(512), 0, stream>>>(
      Ab, Wb, bsc, spans, out);
}